// Round 1
// baseline (376.155 us; speedup 1.0000x reference)
//
#include <hip/hip_runtime.h>
#include <hip/hip_bf16.h>

#define N_RES  2048
#define N_ATOM 32768
#define C_S    384
#define C_OUT  50

// Kernel A: T[r][c] = b[c] + sum_k s[r][k] * W[k][c]   (T is [N_RES][C_OUT])
__global__ __launch_bounds__(64) void lddt_token_table(
    const float* __restrict__ s,   // [N_RES, C_S]
    const float* __restrict__ W,   // [C_S, C_OUT]
    const float* __restrict__ b,   // [C_OUT]
    float* __restrict__ T)         // [N_RES, C_OUT]
{
    __shared__ float srow[C_S];
    const int r = blockIdx.x;
    for (int k = threadIdx.x; k < C_S; k += 64)
        srow[k] = s[(size_t)r * C_S + k];
    __syncthreads();

    const int c = threadIdx.x;
    if (c < C_OUT) {
        // 4 partial accumulators to break the FMA dependency chain
        float a0 = 0.f, a1 = 0.f, a2 = 0.f, a3 = 0.f;
        #pragma unroll 4
        for (int k = 0; k < C_S; k += 4) {
            a0 = fmaf(srow[k + 0], W[(k + 0) * C_OUT + c], a0);
            a1 = fmaf(srow[k + 1], W[(k + 1) * C_OUT + c], a1);
            a2 = fmaf(srow[k + 2], W[(k + 2) * C_OUT + c], a2);
            a3 = fmaf(srow[k + 3], W[(k + 3) * C_OUT + c], a3);
        }
        T[(size_t)r * C_OUT + c] = b[c] + ((a0 + a1) + (a2 + a3));
    }
}

// Kernel B: one 64-lane wave per atom. Scan the one-hot row [N_RES] for the
// position of the 1.0, then copy T[idx][0:50] to out[atom][0:50].
__global__ __launch_bounds__(256) void lddt_gather(
    const float* __restrict__ onehot,  // [N_ATOM, N_RES]
    const float* __restrict__ T,       // [N_RES, C_OUT]
    float* __restrict__ out)           // [N_ATOM, C_OUT]
{
    const int wave = threadIdx.x >> 6;           // 0..3
    const int lane = threadIdx.x & 63;
    const int atom = blockIdx.x * 4 + wave;

    const float4* row = reinterpret_cast<const float4*>(onehot + (size_t)atom * N_RES);

    int found = -1;
    #pragma unroll
    for (int j = 0; j < N_RES / (64 * 4); ++j) {   // 8 iters: 64 lanes x float4
        const int v4 = j * 64 + lane;              // float4 index within row
        float4 v = row[v4];
        const int base = v4 * 4;
        if (v.x > 0.5f) found = base + 0;
        if (v.y > 0.5f) found = base + 1;
        if (v.z > 0.5f) found = base + 2;
        if (v.w > 0.5f) found = base + 3;
    }
    // wave-wide max reduce (exactly one lane holds the true index; rest -1)
    #pragma unroll
    for (int off = 1; off < 64; off <<= 1)
        found = max(found, __shfl_xor(found, off));

    if (lane < C_OUT)
        out[(size_t)atom * C_OUT + lane] = T[(size_t)found * C_OUT + lane];
}

extern "C" void kernel_launch(void* const* d_in, const int* in_sizes, int n_in,
                              void* d_out, int out_size, void* d_ws, size_t ws_size,
                              hipStream_t stream) {
    const float* s      = (const float*)d_in[0];  // [2048, 384]
    const float* onehot = (const float*)d_in[1];  // [32768, 2048]
    const float* W      = (const float*)d_in[2];  // [384, 50]
    const float* b      = (const float*)d_in[3];  // [50]
    float* out = (float*)d_out;                   // [32768, 50]
    float* T   = (float*)d_ws;                    // [2048, 50] scratch

    lddt_token_table<<<N_RES, 64, 0, stream>>>(s, W, b, T);
    lddt_gather<<<N_ATOM / 4, 256, 0, stream>>>(onehot, T, out);
}

// Round 3
// 327.903 us; speedup vs baseline: 1.1472x; 1.1472x over previous
//
#include <hip/hip_runtime.h>
#include <hip/hip_bf16.h>

#define N_RES   2048
#define N_ATOM  32768
#define C_S     384
#define C_OUT   50
#define G_ATOMS 64          // probe spacing: one full-row probe per 64 atoms
#define N_PROBE (N_ATOM / G_ATOMS)   // 512 (+1 sentinel)

// Kernel A: T[r][c] = b[c] + sum_k s[r][k] * W[k][c]   (T is [N_RES][C_OUT])
__global__ __launch_bounds__(64) void lddt_token_table(
    const float* __restrict__ s,   // [N_RES, C_S]
    const float* __restrict__ W,   // [C_S, C_OUT]
    const float* __restrict__ b,   // [C_OUT]
    float* __restrict__ T)         // [N_RES, C_OUT]
{
    __shared__ float srow[C_S];
    const int r = blockIdx.x;
    for (int k = threadIdx.x; k < C_S; k += 64)
        srow[k] = s[(size_t)r * C_S + k];
    __syncthreads();

    const int c = threadIdx.x;
    if (c < C_OUT) {
        float a0 = 0.f, a1 = 0.f, a2 = 0.f, a3 = 0.f;
        #pragma unroll 4
        for (int k = 0; k < C_S; k += 4) {
            a0 = fmaf(srow[k + 0], W[(k + 0) * C_OUT + c], a0);
            a1 = fmaf(srow[k + 1], W[(k + 1) * C_OUT + c], a1);
            a2 = fmaf(srow[k + 2], W[(k + 2) * C_OUT + c], a2);
            a3 = fmaf(srow[k + 3], W[(k + 3) * C_OUT + c], a3);
        }
        T[(size_t)r * C_OUT + c] = b[c] + ((a0 + a1) + (a2 + a3));
    }
}

// Kernel B: probe the token of atom min(g*64, N_ATOM-1) by scanning its full
// one-hot row. One wave per probe. P has N_PROBE+1 entries (last = sentinel
// from the final atom's row, an upper bound for the last group).
__global__ __launch_bounds__(64) void lddt_probe(
    const float* __restrict__ onehot,  // [N_ATOM, N_RES]
    int* __restrict__ P)               // [N_PROBE + 1]
{
    const int g    = blockIdx.x;
    const int atom = min(g * G_ATOMS, N_ATOM - 1);
    const int lane = threadIdx.x;

    const float4* row = reinterpret_cast<const float4*>(onehot + (size_t)atom * N_RES);

    int found = -1;
    #pragma unroll
    for (int j = 0; j < N_RES / (64 * 4); ++j) {   // 8 iters of 64 lanes x float4
        const int v4 = j * 64 + lane;
        float4 v = row[v4];
        const int base = v4 * 4;
        if (v.x > 0.5f) found = base + 0;
        if (v.y > 0.5f) found = base + 1;
        if (v.z > 0.5f) found = base + 2;
        if (v.w > 0.5f) found = base + 3;
    }
    #pragma unroll
    for (int off = 1; off < 64; off <<= 1)
        found = max(found, __shfl_xor(found, off));

    if (lane == 0) P[g] = found;
}

// Kernel C: one wave per atom. Tokens are sorted, so atom a's token lies in
// [P[a/64], P[a/64+1]] — scan only that tiny window (expected ~5 floats),
// then emit T[token][0:50].
__global__ __launch_bounds__(256) void lddt_gather(
    const float* __restrict__ onehot,  // [N_ATOM, N_RES]
    const int* __restrict__ P,         // [N_PROBE + 1]
    const float* __restrict__ T,       // [N_RES, C_OUT]
    float* __restrict__ out)           // [N_ATOM, C_OUT]
{
    const int wave = threadIdx.x >> 6;
    const int lane = threadIdx.x & 63;
    const int atom = blockIdx.x * 4 + wave;
    const int g    = atom >> 6;        // atom / G_ATOMS

    const int lo = P[g];
    const int hi = P[g + 1];

    const float* row = onehot + (size_t)atom * N_RES;

    int found = -1;
    for (int t = lo + lane; t <= hi; t += 64)
        if (row[t] > 0.5f) found = t;

    #pragma unroll
    for (int off = 1; off < 64; off <<= 1)
        found = max(found, __shfl_xor(found, off));

    if (lane < C_OUT)
        out[(size_t)atom * C_OUT + lane] = T[(size_t)found * C_OUT + lane];
}

extern "C" void kernel_launch(void* const* d_in, const int* in_sizes, int n_in,
                              void* d_out, int out_size, void* d_ws, size_t ws_size,
                              hipStream_t stream) {
    const float* s      = (const float*)d_in[0];  // [2048, 384]
    const float* onehot = (const float*)d_in[1];  // [32768, 2048]
    const float* W      = (const float*)d_in[2];  // [384, 50]
    const float* b      = (const float*)d_in[3];  // [50]
    float* out = (float*)d_out;                   // [32768, 50]

    float* T = (float*)d_ws;                      // [2048, 50]
    int*   P = (int*)((char*)d_ws + (size_t)N_RES * C_OUT * sizeof(float));

    lddt_token_table<<<N_RES, 64, 0, stream>>>(s, W, b, T);
    lddt_probe<<<N_PROBE + 1, 64, 0, stream>>>(onehot, P);
    lddt_gather<<<N_ATOM / 4, 256, 0, stream>>>(onehot, P, T, out);
}